// Round 2
// baseline (12266.594 us; speedup 1.0000x reference)
//
#include <hip/hip_runtime.h>

typedef __attribute__((ext_vector_type(8))) short bf16x8;   // 8 bf16 in 4 VGPRs
typedef __attribute__((ext_vector_type(4))) float f32x4;

#define NTT 512
#define NH  512
#define NIN 9
#define NO  3
#define MROWS   32    // batch rows per group

__device__ __forceinline__ short f2bf(float f) {  // RNE fp32 -> bf16
  unsigned u = __builtin_bit_cast(unsigned, f);
  u = (u + 0x7fffu + ((u >> 16) & 1u)) >> 16;
  return (short)u;
}
__device__ __forceinline__ float bf2f(short s) {
  unsigned u = ((unsigned)(unsigned short)s) << 16;
  return __builtin_bit_cast(float, u);
}
__device__ __forceinline__ float sigf(float x) { return 1.f / (1.f + __expf(-x)); }
__device__ __forceinline__ float tanh_fast(float x) { return 1.f - 2.f / (1.f + __expf(2.f * x)); }

// ============================ TAGGED-8 kernel ===============================
// 64 WGs = 8 groups (32 batch rows) x 8 members (64 hidden each), 512 thr/WG.
// vs the 32-member r9 design: 4x less poll traffic (64 vs 256 WGs reading the
// same 64KB group slab), 4x smaller fan-in (8 producers -> less skew), 16 u64
// poll loads/thread instead of 32, and 4x more MFMA per CU so compute actually
// covers part of the exchange latency. Tagged-u32 protocol unchanged (proven).
// g = bid&7 / w = bid>>3 so group members land on one XCD under round-robin
// dispatch (perf heuristic only; correctness is tag-driven).
__global__ __launch_bounds__(512, 2) void lstm_tagged8(
    const float* __restrict__ x, const float* __restrict__ W_ih,
    const float* __restrict__ W_hh, const float* __restrict__ b_ih,
    const float* __restrict__ b_hh, const float* __restrict__ W_fc,
    const float* __restrict__ b_fc, const int* __restrict__ horizon,
    float* __restrict__ out, unsigned* __restrict__ ws32) {
  const int tid  = threadIdx.x;
  const int bid  = blockIdx.x;
  const int g    = bid & 7;    // group: batch rows [32g, 32g+32)
  const int w    = bid >> 3;   // member: hidden [64w, 64w+64)
  const int wid  = tid >> 6;   // wave 0..7
  const int lane = tid & 63;
  const int l15  = lane & 15;
  const int quad = lane >> 4;
  const int hl   = tid & 63;   // update mapping: hidden-local col
  const int rb   = tid >> 6;   // update mapping: rows rb, rb+8, rb+16, rb+24

  // ws (u32): tagged h dbuf [2][8 grp][32 rows][512] = 2 x 512 KB
  unsigned* tbuf0 = ws32;
  unsigned* tbuf1 = ws32 + 131072;

  __shared__ __align__(16) unsigned short hbuf[32][520];  // 1040B rows, b128-aligned
  __shared__ float gbuf[4][64][37];                       // [gate][hloc][brow] pad37
  __shared__ __align__(16) float fcbuf[32][4][8];         // [brow][o][kk-wave]
  __shared__ float xbuf[32][NIN];

  // ---- persistent W_hh hi/lo fragments: wave wid owns N-slices 2wid, 2wid+1 ----
  bf16x8 Bhi[2][16], Blo[2][16];
#pragma unroll
  for (int nt = 0; nt < 2; ++nt) {
    const int s = wid * 2 + nt;                 // slice 0..15 of member's 256 cols
    const int row = (s >> 2) * NH + w * 64 + (s & 3) * 16 + l15;  // global gate row
#pragma unroll
    for (int kt = 0; kt < 16; ++kt) {
      bf16x8 vh, vl;
#pragma unroll
      for (int j = 0; j < 8; ++j) {
        int k = kt * 32 + quad * 8 + j;
        float v = W_hh[(size_t)row * NH + k];
        short hi = f2bf(v);
        vh[j] = hi; vl[j] = f2bf(v - bf2f(hi));
      }
      Bhi[nt][kt] = vh; Blo[nt][kt] = vl;
    }
  }
  // fc tile: wave wid covers K-chunks kt = 2wid, 2wid+1
  bf16x8 Fhi[2], Flo[2];
#pragma unroll
  for (int kk = 0; kk < 2; ++kk) {
    bf16x8 vh, vl;
#pragma unroll
    for (int j = 0; j < 8; ++j) {
      int k = (wid * 2 + kk) * 32 + quad * 8 + j;
      float v = (l15 < NO) ? W_fc[(size_t)l15 * NH + k] : 0.f;
      short hi = f2bf(v);
      vh[j] = hi; vl[j] = f2bf(v - bf2f(hi));
    }
    Fhi[kk] = vh; Flo[kk] = vl;
  }
  // x-path weights + biases in REGISTERS (fp32 exact): 4 gates for hidden hl
  float xwr[4][NIN], bslr[4];
#pragma unroll
  for (int gg = 0; gg < 4; ++gg) {
    const int grow = gg * NH + w * 64 + hl;
    bslr[gg] = b_ih[grow] + b_hh[grow];
#pragma unroll
    for (int k = 0; k < NIN; ++k) xwr[gg][k] = W_ih[grow * NIN + k];
  }
  for (int i = tid; i < 8320; i += 512) ((unsigned*)hbuf)[i] = 0u;  // h_0 = 0
  const float bfc0 = b_fc[0], bfc1 = b_fc[1], bfc2 = b_fc[2];
  const int hor = *horizon;

  // ---- hoisted t-invariant index math ----
  const int r0c = tid / NIN, k0c = tid - r0c * NIN;          // x slice (288 vals)
  const bool x0ok = (tid < MROWS * NIN);
  const float* xp0 = x + (size_t)(g * MROWS + (x0ok ? r0c : 0)) * NTT * NIN + k0c;
  const int ob = tid / NO, oo = tid - ob * NO;               // out write mapping
  const bool ook = (w == 0) && (tid < MROWS * NO);
  const float obias = (oo == 0) ? bfc0 : (oo == 1) ? bfc1 : bfc2;
  float* op = out + ((size_t)(g * MROWS + ob) * NTT) * NO + oo;  // + t*NO per step
  __syncthreads();

  float cst[4] = {0.f, 0.f, 0.f, 0.f};
  int tmod = 0;

  for (int t = 0; t <= NTT; ++t) {
    // x_t slice: issue global load NOW (reg), write LDS after MFMA.
    float xv0 = 0.f;
    if (t < NTT && x0ok) xv0 = xp0[t * NIN];

    // ---- MFMA: 2 N-slices x 2 M-tiles over full K; fc K-chunk pair ----
    f32x4 z4 = {0.f, 0.f, 0.f, 0.f};
    f32x4 accg[2][2] = {{z4, z4}, {z4, z4}}, accf[2] = {z4, z4};
#pragma unroll
    for (int kt = 0; kt < 16; ++kt) {
      bf16x8 a0 = *(const bf16x8*)&hbuf[l15][kt * 32 + quad * 8];
      bf16x8 a1 = *(const bf16x8*)&hbuf[16 + l15][kt * 32 + quad * 8];
#pragma unroll
      for (int nt = 0; nt < 2; ++nt) {
        accg[nt][0] = __builtin_amdgcn_mfma_f32_16x16x32_bf16(a0, Bhi[nt][kt], accg[nt][0], 0, 0, 0);
        accg[nt][1] = __builtin_amdgcn_mfma_f32_16x16x32_bf16(a1, Bhi[nt][kt], accg[nt][1], 0, 0, 0);
        accg[nt][0] = __builtin_amdgcn_mfma_f32_16x16x32_bf16(a0, Blo[nt][kt], accg[nt][0], 0, 0, 0);
        accg[nt][1] = __builtin_amdgcn_mfma_f32_16x16x32_bf16(a1, Blo[nt][kt], accg[nt][1], 0, 0, 0);
      }
      if ((kt >> 1) == wid) {
        int kk = kt & 1;
        accf[0] = __builtin_amdgcn_mfma_f32_16x16x32_bf16(a0, Fhi[kk], accf[0], 0, 0, 0);
        accf[1] = __builtin_amdgcn_mfma_f32_16x16x32_bf16(a1, Fhi[kk], accf[1], 0, 0, 0);
        accf[0] = __builtin_amdgcn_mfma_f32_16x16x32_bf16(a0, Flo[kk], accf[0], 0, 0, 0);
        accf[1] = __builtin_amdgcn_mfma_f32_16x16x32_bf16(a1, Flo[kk], accf[1], 0, 0, 0);
      }
    }
    // stage: D row(b) = mt*16 + quad*4 + r, col = slice*16 + l15
#pragma unroll
    for (int nt = 0; nt < 2; ++nt) {
      const int s = wid * 2 + nt;
      const int gg = s >> 2, hloc = (s & 3) * 16 + l15;
#pragma unroll
      for (int mt = 0; mt < 2; ++mt)
#pragma unroll
        for (int r = 0; r < 4; ++r)
          gbuf[gg][hloc][mt * 16 + quad * 4 + r] = accg[nt][mt][r];
    }
    if (l15 < NO) {
#pragma unroll
      for (int mt = 0; mt < 2; ++mt)
#pragma unroll
        for (int r = 0; r < 4; ++r) fcbuf[mt * 16 + quad * 4 + r][l15][wid] = accf[mt][r];
    }
    if (t < NTT && x0ok) xbuf[r0c][k0c] = xv0;
    __syncthreads();

    if (t == NTT) {  // final fc only
      if (ook) {
        f32x4 pa = *(const f32x4*)&fcbuf[ob][oo][0];
        f32x4 pb = *(const f32x4*)&fcbuf[ob][oo][4];
        op[(t - 1) * NO] = obias + pa[0] + pa[1] + pa[2] + pa[3]
                                 + pb[0] + pb[1] + pb[2] + pb[3];
      }
      break;
    }

    const bool raw = (t < 5) || (tmod == 0);
    const unsigned tg = (unsigned)(t + 1);
    unsigned* dst = ((t & 1) ? tbuf1 : tbuf0) + (size_t)g * 16384;  // u32 slab

    // ---- cell update: thread owns col hl of rows rb, rb+8, rb+16, rb+24 ----
#pragma unroll
    for (int e = 0; e < 4; ++e) {
      const int brow = rb + 8 * e;
      float xin[NIN];
#pragma unroll
      for (int k = 0; k < NIN; ++k) xin[k] = xbuf[brow][k];
      if (!raw) {
        f32x4 p0a = *(const f32x4*)&fcbuf[brow][0][0];
        f32x4 p0b = *(const f32x4*)&fcbuf[brow][0][4];
        f32x4 p1a = *(const f32x4*)&fcbuf[brow][1][0];
        f32x4 p1b = *(const f32x4*)&fcbuf[brow][1][4];
        f32x4 p2a = *(const f32x4*)&fcbuf[brow][2][0];
        f32x4 p2b = *(const f32x4*)&fcbuf[brow][2][4];
        xin[0] = bfc0 + p0a[0] + p0a[1] + p0a[2] + p0a[3] + p0b[0] + p0b[1] + p0b[2] + p0b[3];
        xin[1] = bfc1 + p1a[0] + p1a[1] + p1a[2] + p1a[3] + p1b[0] + p1b[1] + p1b[2] + p1b[3];
        xin[2] = bfc2 + p2a[0] + p2a[1] + p2a[2] + p2a[3] + p2b[0] + p2b[1] + p2b[2] + p2b[3];
      }
      float gv[4];
#pragma unroll
      for (int gg = 0; gg < 4; ++gg) {
        float s = bslr[gg] + gbuf[gg][hl][brow];
#pragma unroll
        for (int k = 0; k < NIN; ++k) s += xin[k] * xwr[gg][k];
        gv[gg] = s;
      }
      float cn = sigf(gv[1]) * cst[e] + sigf(gv[0]) * tanh_fast(gv[2]);
      cst[e] = cn;
      float hn = sigf(gv[3]) * tanh_fast(cn);
      // tagged store: payload+tag in ONE u32 -> atomic consistency for free
      unsigned word = (unsigned)(unsigned short)f2bf(hn) | (tg << 16);
      __hip_atomic_store(&dst[(size_t)brow * NH + w * 64 + hl], word,
                         __ATOMIC_RELAXED, __HIP_MEMORY_SCOPE_AGENT);
    }

    // out[t-1]: member 0 writes (off the exchange critical path)
    if (ook && t > 0) {
      f32x4 pa = *(const f32x4*)&fcbuf[ob][oo][0];
      f32x4 pb = *(const f32x4*)&fcbuf[ob][oo][4];
      op[(t - 1) * NO] = obias + pa[0] + pa[1] + pa[2] + pa[3]
                               + pb[0] + pb[1] + pb[2] + pb[3];
    }

    // ---- exchange: all 16 loads in flight BEFORE any check; batched retry ----
    {
      const unsigned long long* src =
          (const unsigned long long*)(((t & 1) ? tbuf1 : tbuf0) + (size_t)g * 16384);
      const unsigned long long pat =
          ((unsigned long long)tg << 16) | ((unsigned long long)tg << 48);
      unsigned* hb32 = (unsigned*)hbuf;
      unsigned long long v[16];
#pragma unroll
      for (int j = 0; j < 16; ++j)   // one latency exposure, 16 loads in flight
        v[j] = __hip_atomic_load(src + tid + 512 * j,
                                 __ATOMIC_RELAXED, __HIP_MEMORY_SCOPE_AGENT);
      unsigned mask = 0u;
#pragma unroll
      for (int j = 0; j < 16; ++j)
        mask |= (((v[j] ^ pat) & 0xFFFF0000FFFF0000ULL) ? 1u : 0u) << j;
      while (__builtin_expect(mask != 0u, 0)) {
        // batched straggler reload: all failed words re-issued as independent loads
#pragma unroll
        for (int j = 0; j < 16; ++j)
          if (mask & (1u << j))
            v[j] = __hip_atomic_load(src + tid + 512 * j,
                                     __ATOMIC_RELAXED, __HIP_MEMORY_SCOPE_AGENT);
        unsigned m2 = 0u;
#pragma unroll
        for (int j = 0; j < 16; ++j)
          m2 |= (((v[j] ^ pat) & 0xFFFF0000FFFF0000ULL) ? 1u : 0u) << j;
        mask = m2;
      }
#pragma unroll
      for (int j = 0; j < 16; ++j) {
        const int q = tid + 512 * j;
        hb32[(q >> 8) * 260 + (q & 255)] =
            (unsigned)(v[j] & 0xFFFFu) | ((unsigned)(v[j] >> 32) << 16);
      }
      __syncthreads();
    }
    ++tmod; if (tmod == hor) tmod = 0;
  }
}

// ====================== FALLBACK kernel (r4 structure) ======================
#define MEMBERS 32
#define HPW 16
__global__ __launch_bounds__(256, 1) void lstm_fallback(
    const float* __restrict__ x, const float* __restrict__ W_ih,
    const float* __restrict__ W_hh, const float* __restrict__ b_ih,
    const float* __restrict__ b_hh, const float* __restrict__ W_fc,
    const float* __restrict__ b_fc, const int* __restrict__ horizon,
    float* __restrict__ out, unsigned short* __restrict__ ws) {
  const int tid  = threadIdx.x;
  const int bid  = blockIdx.x;
  const int g    = bid >> 5;
  const int w    = bid & 31;
  const int wid  = tid >> 6;
  const int lane = tid & 63;
  const int l15  = lane & 15;
  const int quad = lane >> 4;
  const int hl   = tid & 15;
  const int b0   = tid >> 4;

  unsigned short* buf0 = ws;
  unsigned short* buf1 = ws + 131072;
  int* fl = (int*)(ws + 262144) + g * MEMBERS;

  __shared__ __align__(16) unsigned short hbuf[32][520];
  __shared__ __align__(16) float gbuf[4][16][36];
  __shared__ float fcbuf[4][32][4];
  __shared__ float xbuf[32][NIN];
  __shared__ float xw[64][NIN];
  __shared__ float bsl[64];

  bf16x8 Bhi[16], Blo[16];
#pragma unroll
  for (int kt = 0; kt < 16; ++kt) {
    bf16x8 vh, vl;
    const int row = wid * NH + w * HPW + l15;
#pragma unroll
    for (int j = 0; j < 8; ++j) {
      int k = kt * 32 + quad * 8 + j;
      float v = W_hh[(size_t)row * NH + k];
      short hi = f2bf(v);
      vh[j] = hi; vl[j] = f2bf(v - bf2f(hi));
    }
    Bhi[kt] = vh; Blo[kt] = vl;
  }
  bf16x8 Fhi[4], Flo[4];
#pragma unroll
  for (int kk = 0; kk < 4; ++kk) {
    bf16x8 vh, vl;
#pragma unroll
    for (int j = 0; j < 8; ++j) {
      int k = (wid * 4 + kk) * 32 + quad * 8 + j;
      float v = (l15 < NO) ? W_fc[(size_t)l15 * NH + k] : 0.f;
      short hi = f2bf(v);
      vh[j] = hi; vl[j] = f2bf(v - bf2f(hi));
    }
    Fhi[kk] = vh; Flo[kk] = vl;
  }
  if (tid < 64) {
    int grow = (tid >> 4) * NH + w * HPW + (tid & 15);
    bsl[tid] = b_ih[grow] + b_hh[grow];
#pragma unroll
    for (int k = 0; k < NIN; ++k) xw[tid][k] = W_ih[grow * NIN + k];
  }
  for (int i = tid; i < 8320; i += 256) ((unsigned*)hbuf)[i] = 0u;
  const float bfc0 = b_fc[0], bfc1 = b_fc[1], bfc2 = b_fc[2];
  const int hor = *horizon;
  __syncthreads();

  float cst[2] = {0.f, 0.f};
  int tmod = 0;

  for (int t = 0; t <= NTT; ++t) {
    float xv0 = 0.f, xv1 = 0.f;
    int r0 = 0, k0 = 0, r1 = 0, k1 = 0;
    if (t < NTT) {
      r0 = tid / NIN; k0 = tid - r0 * NIN;
      if (r0 < MROWS) xv0 = x[((size_t)(g * MROWS + r0) * NTT + t) * NIN + k0];
      int i1 = tid + 256;
      r1 = i1 / NIN; k1 = i1 - r1 * NIN;
      if (i1 < MROWS * NIN) xv1 = x[((size_t)(g * MROWS + r1) * NTT + t) * NIN + k1];
    }
    f32x4 z4 = {0.f, 0.f, 0.f, 0.f};
    f32x4 accg[2] = {z4, z4}, accf[2] = {z4, z4};
#pragma unroll
    for (int kt = 0; kt < 16; ++kt) {
      bf16x8 a0 = *(const bf16x8*)&hbuf[l15][kt * 32 + quad * 8];
      bf16x8 a1 = *(const bf16x8*)&hbuf[16 + l15][kt * 32 + quad * 8];
      accg[0] = __builtin_amdgcn_mfma_f32_16x16x32_bf16(a0, Bhi[kt], accg[0], 0, 0, 0);
      accg[1] = __builtin_amdgcn_mfma_f32_16x16x32_bf16(a1, Bhi[kt], accg[1], 0, 0, 0);
      accg[0] = __builtin_amdgcn_mfma_f32_16x16x32_bf16(a0, Blo[kt], accg[0], 0, 0, 0);
      accg[1] = __builtin_amdgcn_mfma_f32_16x16x32_bf16(a1, Blo[kt], accg[1], 0, 0, 0);
      if ((kt >> 2) == wid) {
        int kk = kt & 3;
        accf[0] = __builtin_amdgcn_mfma_f32_16x16x32_bf16(a0, Fhi[kk], accf[0], 0, 0, 0);
        accf[1] = __builtin_amdgcn_mfma_f32_16x16x32_bf16(a1, Fhi[kk], accf[1], 0, 0, 0);
        accf[0] = __builtin_amdgcn_mfma_f32_16x16x32_bf16(a0, Flo[kk], accf[0], 0, 0, 0);
        accf[1] = __builtin_amdgcn_mfma_f32_16x16x32_bf16(a1, Flo[kk], accf[1], 0, 0, 0);
      }
    }
#pragma unroll
    for (int mt = 0; mt < 2; ++mt)
      *(f32x4*)&gbuf[wid][l15][mt * 16 + quad * 4] = accg[mt];
    if (l15 < NO) {
#pragma unroll
      for (int mt = 0; mt < 2; ++mt)
#pragma unroll
        for (int r = 0; r < 4; ++r) fcbuf[wid][mt * 16 + quad * 4 + r][l15] = accf[mt][r];
    }
    if (t < NTT) {
      if (r0 < MROWS) xbuf[r0][k0] = xv0;
      if (tid < MROWS * NIN - 256) xbuf[r1][k1] = xv1;
    }
    __syncthreads();

    if (t == NTT) {
      if (w == 0 && tid < MROWS * NO) {
        int b = tid / NO, o = tid - b * NO;
        float bo = (o == 0) ? bfc0 : (o == 1) ? bfc1 : bfc2;
        out[((size_t)(g * MROWS + b) * NTT + (t - 1)) * NO + o] =
            bo + fcbuf[0][b][o] + fcbuf[1][b][o] + fcbuf[2][b][o] + fcbuf[3][b][o];
      }
      break;
    }

    const bool raw = (t < 5) || (tmod == 0);
    unsigned long long* nxt64 =
        (unsigned long long*)(((t & 1) ? buf1 : buf0) + (size_t)g * (MROWS * NH));
#pragma unroll
    for (int e = 0; e < 2; ++e) {
      int b = b0 + 16 * e;
      float xin[NIN];
#pragma unroll
      for (int k = 0; k < NIN; ++k) xin[k] = xbuf[b][k];
      if (!raw) {
        xin[0] = bfc0 + fcbuf[0][b][0] + fcbuf[1][b][0] + fcbuf[2][b][0] + fcbuf[3][b][0];
        xin[1] = bfc1 + fcbuf[0][b][1] + fcbuf[1][b][1] + fcbuf[2][b][1] + fcbuf[3][b][1];
        xin[2] = bfc2 + fcbuf[0][b][2] + fcbuf[1][b][2] + fcbuf[2][b][2] + fcbuf[3][b][2];
      }
      float gv[4];
#pragma unroll
      for (int gg = 0; gg < 4; ++gg) {
        int r = gg * 16 + hl;
        float s = bsl[r] + gbuf[gg][hl][b];
#pragma unroll
        for (int k = 0; k < NIN; ++k) s += xin[k] * xw[r][k];
        gv[gg] = s;
      }
      float cn = sigf(gv[1]) * cst[e] + sigf(gv[0]) * tanh_fast(gv[2]);
      cst[e] = cn;
      float hn = sigf(gv[3]) * tanh_fast(cn);
      unsigned hb16 = (unsigned)(unsigned short)f2bf(hn);
      unsigned pair = hb16 | ((unsigned)__shfl_xor((int)hb16, 1, 64) << 16);
      unsigned long long v64 =
          (unsigned long long)pair |
          ((unsigned long long)(unsigned)__shfl_xor((int)pair, 2, 64) << 32);
      if ((hl & 3) == 0)
        __hip_atomic_store(&nxt64[(size_t)b * 128 + w * 4 + (hl >> 2)], v64,
                           __ATOMIC_RELAXED, __HIP_MEMORY_SCOPE_AGENT);
    }
    asm volatile("s_waitcnt vmcnt(0)" ::: "memory");
    __syncthreads();

    if (tid == 0)
      __hip_atomic_store(&fl[w], t + 1, __ATOMIC_RELAXED, __HIP_MEMORY_SCOPE_AGENT);
    if (w == 0 && t > 0 && tid < MROWS * NO) {
      int b = tid / NO, o = tid - b * NO;
      float bo = (o == 0) ? bfc0 : (o == 1) ? bfc1 : bfc2;
      out[((size_t)(g * MROWS + b) * NTT + (t - 1)) * NO + o] =
          bo + fcbuf[0][b][o] + fcbuf[1][b][o] + fcbuf[2][b][o] + fcbuf[3][b][o];
    }
    if (tid < MEMBERS) {
      while (__hip_atomic_load(&fl[tid], __ATOMIC_RELAXED,
                               __HIP_MEMORY_SCOPE_AGENT) < t + 1)
        __builtin_amdgcn_s_sleep(1);
    }
    __syncthreads();

    const unsigned long long* src =
        (const unsigned long long*)(((t & 1) ? buf1 : buf0) + (size_t)g * (MROWS * NH));
#pragma unroll
    for (int j = 0; j < 16; ++j) {
      int idx = tid + 256 * j;
      unsigned long long v =
          __hip_atomic_load(src + idx, __ATOMIC_RELAXED, __HIP_MEMORY_SCOPE_AGENT);
      *(unsigned long long*)&hbuf[idx >> 7][(idx & 127) * 4] = v;
    }
    __syncthreads();
    ++tmod; if (tmod == hor) tmod = 0;
  }
}

extern "C" void kernel_launch(void* const* d_in, const int* in_sizes, int n_in,
                              void* d_out, int out_size, void* d_ws, size_t ws_size,
                              hipStream_t stream) {
  (void)in_sizes; (void)n_in; (void)out_size;
  const float* x    = (const float*)d_in[0];
  const float* W_ih = (const float*)d_in[1];
  const float* W_hh = (const float*)d_in[2];
  const float* b_ih = (const float*)d_in[3];
  const float* b_hh = (const float*)d_in[4];
  const float* W_fc = (const float*)d_in[5];
  const float* b_fc = (const float*)d_in[6];
  const int*   hor  = (const int*)d_in[7];
  if (ws_size >= (size_t)1048576) {
    lstm_tagged8<<<dim3(64), dim3(512), 0, stream>>>(
        x, W_ih, W_hh, b_ih, b_hh, W_fc, b_fc, hor,
        (float*)d_out, (unsigned*)d_ws);
  } else {
    lstm_fallback<<<dim3(256), dim3(256), 0, stream>>>(
        x, W_ih, W_hh, b_ih, b_hh, W_fc, b_fc, hor,
        (float*)d_out, (unsigned short*)d_ws);
  }
}

// Round 3
// 4087.291 us; speedup vs baseline: 3.0012x; 3.0012x over previous
//
#include <hip/hip_runtime.h>

typedef __attribute__((ext_vector_type(8))) short bf16x8;   // 8 bf16 in 4 VGPRs
typedef __attribute__((ext_vector_type(4))) float f32x4;

#define NTT 512
#define NH  512
#define NIN 9
#define NO  3
#define MROWS   32    // batch rows per group

__device__ __forceinline__ short f2bf(float f) {  // RNE fp32 -> bf16
  unsigned u = __builtin_bit_cast(unsigned, f);
  u = (u + 0x7fffu + ((u >> 16) & 1u)) >> 16;
  return (short)u;
}
__device__ __forceinline__ float bf2f(short s) {
  unsigned u = ((unsigned)(unsigned short)s) << 16;
  return __builtin_bit_cast(float, u);
}
__device__ __forceinline__ float sigf(float x) { return 1.f / (1.f + __expf(-x)); }
__device__ __forceinline__ float tanh_fast(float x) { return 1.f - 2.f / (1.f + __expf(2.f * x)); }

// ============================ TAGGED-16 kernel ==============================
// 128 WGs = 8 groups (32 batch rows) x 16 members (32 hidden each), 256 thr.
// vs r9 (32 members): half the WGs polling each 64KB group slab (8MB/step vs
// 16MB device-wide), half the producer fan-in (16 vs 32 -> less straggler
// skew), 2x MFMA per wave. vs round-2 (8 members @ 512thr): VGPR-feasible —
// __launch_bounds__(256,1) gives the 512-VGPR budget; peak live ~400, so the
// 256-VGPR persistent W_hh hi/lo set stays in registers (r2 spilled at the
// 128 cap; tripwire: WRITE_SIZE must stay ~264MB, not ~940MB).
// bid = w*8+g so a group's 16 members share an XCD under round-robin dispatch
// (perf heuristic only; correctness is tag-driven).
__global__ __launch_bounds__(256, 1) void lstm_tagged16(
    const float* __restrict__ x, const float* __restrict__ W_ih,
    const float* __restrict__ W_hh, const float* __restrict__ b_ih,
    const float* __restrict__ b_hh, const float* __restrict__ W_fc,
    const float* __restrict__ b_fc, const int* __restrict__ horizon,
    float* __restrict__ out, unsigned* __restrict__ ws32) {
  const int tid  = threadIdx.x;
  const int bid  = blockIdx.x;
  const int g    = bid & 7;    // group: batch rows [32g, 32g+32)
  const int w    = bid >> 3;   // member 0..15: hidden [32w, 32w+32)
  const int wid  = tid >> 6;   // wave 0..3
  const int lane = tid & 63;
  const int l15  = lane & 15;
  const int quad = lane >> 4;
  const int hl   = tid & 31;   // update mapping: hidden-local col 0..31
  const int rb   = tid >> 5;   // update mapping: rows rb+8e, e=0..3

  // ws (u32): tagged h dbuf [2][8 grp][32 rows][512] = 2 x 512 KB
  unsigned* tbuf0 = ws32;
  unsigned* tbuf1 = ws32 + 131072;

  __shared__ __align__(16) unsigned short hbuf[32][520];  // 1040B rows, b128-aligned
  __shared__ __align__(16) float gbuf[4][32][36];         // [gate][hloc][brow] 144B stride
  __shared__ float fcbuf[4][32][4];                       // [wave(K-split)][b][o]
  __shared__ float xbuf[32][NIN];
  __shared__ float xw[128][NIN];                          // W_ih rows (gate*32+hl)
  __shared__ float bsl[128];

  // ---- persistent W_hh hi/lo: wave wid owns N-slices s=2wid, 2wid+1 ----
  // slice s (0..7): gate s>>1, member cols (s&1)*16 + [0,16)
  bf16x8 Bhi[2][16], Blo[2][16];
#pragma unroll
  for (int nt = 0; nt < 2; ++nt) {
    const int s = wid * 2 + nt;
    const int row = (s >> 1) * NH + w * 32 + (s & 1) * 16 + l15;  // global gate row
#pragma unroll
    for (int kt = 0; kt < 16; ++kt) {
      bf16x8 vh, vl;
#pragma unroll
      for (int j = 0; j < 8; ++j) {
        int k = kt * 32 + quad * 8 + j;
        float v = W_hh[(size_t)row * NH + k];
        short hi = f2bf(v);
        vh[j] = hi; vl[j] = f2bf(v - bf2f(hi));
      }
      Bhi[nt][kt] = vh; Blo[nt][kt] = vl;
    }
  }
  // fc tile: wave wid covers K quarter kt = 4wid..4wid+3
  bf16x8 Fhi[4], Flo[4];
#pragma unroll
  for (int kk = 0; kk < 4; ++kk) {
    bf16x8 vh, vl;
#pragma unroll
    for (int j = 0; j < 8; ++j) {
      int k = (wid * 4 + kk) * 32 + quad * 8 + j;
      float v = (l15 < NO) ? W_fc[(size_t)l15 * NH + k] : 0.f;
      short hi = f2bf(v);
      vh[j] = hi; vl[j] = f2bf(v - bf2f(hi));
    }
    Fhi[kk] = vh; Flo[kk] = vl;
  }
  if (tid < 128) {  // x-path weights + biases, fp32 exact, in LDS
    int grow = (tid >> 5) * NH + w * 32 + (tid & 31);
    bsl[tid] = b_ih[grow] + b_hh[grow];
#pragma unroll
    for (int k = 0; k < NIN; ++k) xw[tid][k] = W_ih[grow * NIN + k];
  }
  for (int i = tid; i < 8320; i += 256) ((unsigned*)hbuf)[i] = 0u;  // h_0 = 0
  const float bfc0 = b_fc[0], bfc1 = b_fc[1], bfc2 = b_fc[2];
  const int hor = *horizon;

  // ---- hoisted t-invariant index math ----
  const int r0c = tid / NIN, k0c = tid - r0c * NIN;          // x slice part 0
  const int i1c = tid + 256;
  const int r1c = i1c / NIN, k1c = i1c - r1c * NIN;          // x slice part 1
  const bool x0ok = (r0c < MROWS), x1ok = (i1c < MROWS * NIN);
  const float* xp0 = x + (size_t)(g * MROWS + (x0ok ? r0c : 0)) * NTT * NIN + k0c;
  const float* xp1 = x + (size_t)(g * MROWS + (x1ok ? r1c : 0)) * NTT * NIN + k1c;
  const int ob = tid / NO, oo = tid - ob * NO;               // out write mapping
  const bool ook = (w == 0) && (tid < MROWS * NO);
  const float obias = (oo == 0) ? bfc0 : (oo == 1) ? bfc1 : bfc2;
  float* op = out + ((size_t)(g * MROWS + ob) * NTT) * NO + oo;  // + t*NO per step
  __syncthreads();

  float cst[4] = {0.f, 0.f, 0.f, 0.f};
  int tmod = 0;

  for (int t = 0; t <= NTT; ++t) {
    // x_t slice: issue global loads NOW (regs), write LDS after MFMA.
    float xv0 = 0.f, xv1 = 0.f;
    if (t < NTT) {
      if (x0ok) xv0 = xp0[t * NIN];
      if (x1ok) xv1 = xp1[t * NIN];
    }

    // ---- MFMA: 2 N-slices x 2 M-tiles over full K; fc K-quarter ----
    f32x4 z4 = {0.f, 0.f, 0.f, 0.f};
    f32x4 accg[2][2] = {{z4, z4}, {z4, z4}}, accf[2] = {z4, z4};
#pragma unroll
    for (int kt = 0; kt < 16; ++kt) {
      bf16x8 a0 = *(const bf16x8*)&hbuf[l15][kt * 32 + quad * 8];
      bf16x8 a1 = *(const bf16x8*)&hbuf[16 + l15][kt * 32 + quad * 8];
#pragma unroll
      for (int nt = 0; nt < 2; ++nt) {
        accg[nt][0] = __builtin_amdgcn_mfma_f32_16x16x32_bf16(a0, Bhi[nt][kt], accg[nt][0], 0, 0, 0);
        accg[nt][1] = __builtin_amdgcn_mfma_f32_16x16x32_bf16(a1, Bhi[nt][kt], accg[nt][1], 0, 0, 0);
        accg[nt][0] = __builtin_amdgcn_mfma_f32_16x16x32_bf16(a0, Blo[nt][kt], accg[nt][0], 0, 0, 0);
        accg[nt][1] = __builtin_amdgcn_mfma_f32_16x16x32_bf16(a1, Blo[nt][kt], accg[nt][1], 0, 0, 0);
      }
      if ((kt >> 2) == wid) {
        int kk = kt & 3;
        accf[0] = __builtin_amdgcn_mfma_f32_16x16x32_bf16(a0, Fhi[kk], accf[0], 0, 0, 0);
        accf[1] = __builtin_amdgcn_mfma_f32_16x16x32_bf16(a1, Fhi[kk], accf[1], 0, 0, 0);
        accf[0] = __builtin_amdgcn_mfma_f32_16x16x32_bf16(a0, Flo[kk], accf[0], 0, 0, 0);
        accf[1] = __builtin_amdgcn_mfma_f32_16x16x32_bf16(a1, Flo[kk], accf[1], 0, 0, 0);
      }
    }
    // stage: D row(b) = mt*16 + quad*4 + r, col = slice hloc
#pragma unroll
    for (int nt = 0; nt < 2; ++nt) {
      const int s = wid * 2 + nt;
      const int gg = s >> 1, hloc = (s & 1) * 16 + l15;
#pragma unroll
      for (int mt = 0; mt < 2; ++mt)
        *(f32x4*)&gbuf[gg][hloc][mt * 16 + quad * 4] = accg[nt][mt];
    }
    if (l15 < NO) {
#pragma unroll
      for (int mt = 0; mt < 2; ++mt)
#pragma unroll
        for (int r = 0; r < 4; ++r) fcbuf[wid][mt * 16 + quad * 4 + r][l15] = accf[mt][r];
    }
    if (t < NTT) {
      if (x0ok) xbuf[r0c][k0c] = xv0;
      if (x1ok) xbuf[r1c][k1c] = xv1;
    }
    __syncthreads();

    if (t == NTT) {  // final fc only
      if (ook)
        op[(t - 1) * NO] =
            obias + fcbuf[0][ob][oo] + fcbuf[1][ob][oo] + fcbuf[2][ob][oo] + fcbuf[3][ob][oo];
      break;
    }

    const bool raw = (t < 5) || (tmod == 0);
    const unsigned tg = (unsigned)(t + 1);
    unsigned* dst = ((t & 1) ? tbuf1 : tbuf0) + (size_t)g * 16384;  // u32 slab

    // ---- cell update: thread owns col hl of rows rb+8e, e=0..3 ----
#pragma unroll
    for (int e = 0; e < 4; ++e) {
      const int brow = rb + 8 * e;
      float xin[NIN];
#pragma unroll
      for (int k = 0; k < NIN; ++k) xin[k] = xbuf[brow][k];
      if (!raw) {
        xin[0] = bfc0 + fcbuf[0][brow][0] + fcbuf[1][brow][0] + fcbuf[2][brow][0] + fcbuf[3][brow][0];
        xin[1] = bfc1 + fcbuf[0][brow][1] + fcbuf[1][brow][1] + fcbuf[2][brow][1] + fcbuf[3][brow][1];
        xin[2] = bfc2 + fcbuf[0][brow][2] + fcbuf[1][brow][2] + fcbuf[2][brow][2] + fcbuf[3][brow][2];
      }
      float gv[4];
#pragma unroll
      for (int gg = 0; gg < 4; ++gg) {
        const int r = gg * 32 + hl;
        float s = bsl[r] + gbuf[gg][hl][brow];
#pragma unroll
        for (int k = 0; k < NIN; ++k) s += xin[k] * xw[r][k];
        gv[gg] = s;
      }
      float cn = sigf(gv[1]) * cst[e] + sigf(gv[0]) * tanh_fast(gv[2]);
      cst[e] = cn;
      float hn = sigf(gv[3]) * tanh_fast(cn);
      // tagged store: payload+tag in ONE u32 -> atomic consistency for free
      unsigned word = (unsigned)(unsigned short)f2bf(hn) | (tg << 16);
      __hip_atomic_store(&dst[(size_t)brow * NH + w * 32 + hl], word,
                         __ATOMIC_RELAXED, __HIP_MEMORY_SCOPE_AGENT);
    }

    // out[t-1]: member 0 writes (off the exchange critical path)
    if (ook && t > 0)
      op[(t - 1) * NO] =
          obias + fcbuf[0][ob][oo] + fcbuf[1][ob][oo] + fcbuf[2][ob][oo] + fcbuf[3][ob][oo];

    // ---- exchange: all 32 loads in flight BEFORE any check; batched retry ----
    {
      const unsigned long long* src =
          (const unsigned long long*)(((t & 1) ? tbuf1 : tbuf0) + (size_t)g * 16384);
      const unsigned long long pat =
          ((unsigned long long)tg << 16) | ((unsigned long long)tg << 48);
      unsigned* hb32 = (unsigned*)hbuf;
      unsigned long long v[32];
#pragma unroll
      for (int j = 0; j < 32; ++j)   // one latency exposure, 32 loads in flight
        v[j] = __hip_atomic_load(src + tid + 256 * j,
                                 __ATOMIC_RELAXED, __HIP_MEMORY_SCOPE_AGENT);
      unsigned mask = 0u;
#pragma unroll
      for (int j = 0; j < 32; ++j)
        mask |= (((v[j] ^ pat) & 0xFFFF0000FFFF0000ULL) ? 1u : 0u) << j;
      while (__builtin_expect(mask != 0u, 0)) {
        // batched straggler reload: all failed words re-issued as independent loads
#pragma unroll
        for (int j = 0; j < 32; ++j)
          if (mask & (1u << j))
            v[j] = __hip_atomic_load(src + tid + 256 * j,
                                     __ATOMIC_RELAXED, __HIP_MEMORY_SCOPE_AGENT);
        unsigned m2 = 0u;
#pragma unroll
        for (int j = 0; j < 32; ++j)
          m2 |= (((v[j] ^ pat) & 0xFFFF0000FFFF0000ULL) ? 1u : 0u) << j;
        mask = m2;
      }
#pragma unroll
      for (int j = 0; j < 32; ++j) {
        const int q = tid + 256 * j;
        hb32[(q >> 8) * 260 + (q & 255)] =
            (unsigned)(v[j] & 0xFFFFu) | ((unsigned)(v[j] >> 32) << 16);
      }
      __syncthreads();
    }
    ++tmod; if (tmod == hor) tmod = 0;
  }
}

// ====================== FALLBACK kernel (r4 structure) ======================
#define MEMBERS 32
#define HPW 16
__global__ __launch_bounds__(256, 1) void lstm_fallback(
    const float* __restrict__ x, const float* __restrict__ W_ih,
    const float* __restrict__ W_hh, const float* __restrict__ b_ih,
    const float* __restrict__ b_hh, const float* __restrict__ W_fc,
    const float* __restrict__ b_fc, const int* __restrict__ horizon,
    float* __restrict__ out, unsigned short* __restrict__ ws) {
  const int tid  = threadIdx.x;
  const int bid  = blockIdx.x;
  const int g    = bid >> 5;
  const int w    = bid & 31;
  const int wid  = tid >> 6;
  const int lane = tid & 63;
  const int l15  = lane & 15;
  const int quad = lane >> 4;
  const int hl   = tid & 15;
  const int b0   = tid >> 4;

  unsigned short* buf0 = ws;
  unsigned short* buf1 = ws + 131072;
  int* fl = (int*)(ws + 262144) + g * MEMBERS;

  __shared__ __align__(16) unsigned short hbuf[32][520];
  __shared__ __align__(16) float gbuf[4][16][36];
  __shared__ float fcbuf[4][32][4];
  __shared__ float xbuf[32][NIN];
  __shared__ float xw[64][NIN];
  __shared__ float bsl[64];

  bf16x8 Bhi[16], Blo[16];
#pragma unroll
  for (int kt = 0; kt < 16; ++kt) {
    bf16x8 vh, vl;
    const int row = wid * NH + w * HPW + l15;
#pragma unroll
    for (int j = 0; j < 8; ++j) {
      int k = kt * 32 + quad * 8 + j;
      float v = W_hh[(size_t)row * NH + k];
      short hi = f2bf(v);
      vh[j] = hi; vl[j] = f2bf(v - bf2f(hi));
    }
    Bhi[kt] = vh; Blo[kt] = vl;
  }
  bf16x8 Fhi[4], Flo[4];
#pragma unroll
  for (int kk = 0; kk < 4; ++kk) {
    bf16x8 vh, vl;
#pragma unroll
    for (int j = 0; j < 8; ++j) {
      int k = (wid * 4 + kk) * 32 + quad * 8 + j;
      float v = (l15 < NO) ? W_fc[(size_t)l15 * NH + k] : 0.f;
      short hi = f2bf(v);
      vh[j] = hi; vl[j] = f2bf(v - bf2f(hi));
    }
    Fhi[kk] = vh; Flo[kk] = vl;
  }
  if (tid < 64) {
    int grow = (tid >> 4) * NH + w * HPW + (tid & 15);
    bsl[tid] = b_ih[grow] + b_hh[grow];
#pragma unroll
    for (int k = 0; k < NIN; ++k) xw[tid][k] = W_ih[grow * NIN + k];
  }
  for (int i = tid; i < 8320; i += 256) ((unsigned*)hbuf)[i] = 0u;
  const float bfc0 = b_fc[0], bfc1 = b_fc[1], bfc2 = b_fc[2];
  const int hor = *horizon;
  __syncthreads();

  float cst[2] = {0.f, 0.f};
  int tmod = 0;

  for (int t = 0; t <= NTT; ++t) {
    float xv0 = 0.f, xv1 = 0.f;
    int r0 = 0, k0 = 0, r1 = 0, k1 = 0;
    if (t < NTT) {
      r0 = tid / NIN; k0 = tid - r0 * NIN;
      if (r0 < MROWS) xv0 = x[((size_t)(g * MROWS + r0) * NTT + t) * NIN + k0];
      int i1 = tid + 256;
      r1 = i1 / NIN; k1 = i1 - r1 * NIN;
      if (i1 < MROWS * NIN) xv1 = x[((size_t)(g * MROWS + r1) * NTT + t) * NIN + k1];
    }
    f32x4 z4 = {0.f, 0.f, 0.f, 0.f};
    f32x4 accg[2] = {z4, z4}, accf[2] = {z4, z4};
#pragma unroll
    for (int kt = 0; kt < 16; ++kt) {
      bf16x8 a0 = *(const bf16x8*)&hbuf[l15][kt * 32 + quad * 8];
      bf16x8 a1 = *(const bf16x8*)&hbuf[16 + l15][kt * 32 + quad * 8];
      accg[0] = __builtin_amdgcn_mfma_f32_16x16x32_bf16(a0, Bhi[kt], accg[0], 0, 0, 0);
      accg[1] = __builtin_amdgcn_mfma_f32_16x16x32_bf16(a1, Bhi[kt], accg[1], 0, 0, 0);
      accg[0] = __builtin_amdgcn_mfma_f32_16x16x32_bf16(a0, Blo[kt], accg[0], 0, 0, 0);
      accg[1] = __builtin_amdgcn_mfma_f32_16x16x32_bf16(a1, Blo[kt], accg[1], 0, 0, 0);
      if ((kt >> 2) == wid) {
        int kk = kt & 3;
        accf[0] = __builtin_amdgcn_mfma_f32_16x16x32_bf16(a0, Fhi[kk], accf[0], 0, 0, 0);
        accf[1] = __builtin_amdgcn_mfma_f32_16x16x32_bf16(a1, Fhi[kk], accf[1], 0, 0, 0);
        accf[0] = __builtin_amdgcn_mfma_f32_16x16x32_bf16(a0, Flo[kk], accf[0], 0, 0, 0);
        accf[1] = __builtin_amdgcn_mfma_f32_16x16x32_bf16(a1, Flo[kk], accf[1], 0, 0, 0);
      }
    }
#pragma unroll
    for (int mt = 0; mt < 2; ++mt)
      *(f32x4*)&gbuf[wid][l15][mt * 16 + quad * 4] = accg[mt];
    if (l15 < NO) {
#pragma unroll
      for (int mt = 0; mt < 2; ++mt)
#pragma unroll
        for (int r = 0; r < 4; ++r) fcbuf[wid][mt * 16 + quad * 4 + r][l15] = accf[mt][r];
    }
    if (t < NTT) {
      if (r0 < MROWS) xbuf[r0][k0] = xv0;
      if (tid < MROWS * NIN - 256) xbuf[r1][k1] = xv1;
    }
    __syncthreads();

    if (t == NTT) {
      if (w == 0 && tid < MROWS * NO) {
        int b = tid / NO, o = tid - b * NO;
        float bo = (o == 0) ? bfc0 : (o == 1) ? bfc1 : bfc2;
        out[((size_t)(g * MROWS + b) * NTT + (t - 1)) * NO + o] =
            bo + fcbuf[0][b][o] + fcbuf[1][b][o] + fcbuf[2][b][o] + fcbuf[3][b][o];
      }
      break;
    }

    const bool raw = (t < 5) || (tmod == 0);
    unsigned long long* nxt64 =
        (unsigned long long*)(((t & 1) ? buf1 : buf0) + (size_t)g * (MROWS * NH));
#pragma unroll
    for (int e = 0; e < 2; ++e) {
      int b = b0 + 16 * e;
      float xin[NIN];
#pragma unroll
      for (int k = 0; k < NIN; ++k) xin[k] = xbuf[b][k];
      if (!raw) {
        xin[0] = bfc0 + fcbuf[0][b][0] + fcbuf[1][b][0] + fcbuf[2][b][0] + fcbuf[3][b][0];
        xin[1] = bfc1 + fcbuf[0][b][1] + fcbuf[1][b][1] + fcbuf[2][b][1] + fcbuf[3][b][1];
        xin[2] = bfc2 + fcbuf[0][b][2] + fcbuf[1][b][2] + fcbuf[2][b][2] + fcbuf[3][b][2];
      }
      float gv[4];
#pragma unroll
      for (int gg = 0; gg < 4; ++gg) {
        int r = gg * 16 + hl;
        float s = bsl[r] + gbuf[gg][hl][b];
#pragma unroll
        for (int k = 0; k < NIN; ++k) s += xin[k] * xw[r][k];
        gv[gg] = s;
      }
      float cn = sigf(gv[1]) * cst[e] + sigf(gv[0]) * tanh_fast(gv[2]);
      cst[e] = cn;
      float hn = sigf(gv[3]) * tanh_fast(cn);
      unsigned hb16 = (unsigned)(unsigned short)f2bf(hn);
      unsigned pair = hb16 | ((unsigned)__shfl_xor((int)hb16, 1, 64) << 16);
      unsigned long long v64 =
          (unsigned long long)pair |
          ((unsigned long long)(unsigned)__shfl_xor((int)pair, 2, 64) << 32);
      if ((hl & 3) == 0)
        __hip_atomic_store(&nxt64[(size_t)b * 128 + w * 4 + (hl >> 2)], v64,
                           __ATOMIC_RELAXED, __HIP_MEMORY_SCOPE_AGENT);
    }
    asm volatile("s_waitcnt vmcnt(0)" ::: "memory");
    __syncthreads();

    if (tid == 0)
      __hip_atomic_store(&fl[w], t + 1, __ATOMIC_RELAXED, __HIP_MEMORY_SCOPE_AGENT);
    if (w == 0 && t > 0 && tid < MROWS * NO) {
      int b = tid / NO, o = tid - b * NO;
      float bo = (o == 0) ? bfc0 : (o == 1) ? bfc1 : bfc2;
      out[((size_t)(g * MROWS + b) * NTT + (t - 1)) * NO + o] =
          bo + fcbuf[0][b][o] + fcbuf[1][b][o] + fcbuf[2][b][o] + fcbuf[3][b][o];
    }
    if (tid < MEMBERS) {
      while (__hip_atomic_load(&fl[tid], __ATOMIC_RELAXED,
                               __HIP_MEMORY_SCOPE_AGENT) < t + 1)
        __builtin_amdgcn_s_sleep(1);
    }
    __syncthreads();

    const unsigned long long* src =
        (const unsigned long long*)(((t & 1) ? buf1 : buf0) + (size_t)g * (MROWS * NH));
#pragma unroll
    for (int j = 0; j < 16; ++j) {
      int idx = tid + 256 * j;
      unsigned long long v =
          __hip_atomic_load(src + idx, __ATOMIC_RELAXED, __HIP_MEMORY_SCOPE_AGENT);
      *(unsigned long long*)&hbuf[idx >> 7][(idx & 127) * 4] = v;
    }
    __syncthreads();
    ++tmod; if (tmod == hor) tmod = 0;
  }
}

extern "C" void kernel_launch(void* const* d_in, const int* in_sizes, int n_in,
                              void* d_out, int out_size, void* d_ws, size_t ws_size,
                              hipStream_t stream) {
  (void)in_sizes; (void)n_in; (void)out_size;
  const float* x    = (const float*)d_in[0];
  const float* W_ih = (const float*)d_in[1];
  const float* W_hh = (const float*)d_in[2];
  const float* b_ih = (const float*)d_in[3];
  const float* b_hh = (const float*)d_in[4];
  const float* W_fc = (const float*)d_in[5];
  const float* b_fc = (const float*)d_in[6];
  const int*   hor  = (const int*)d_in[7];
  if (ws_size >= (size_t)1048576) {
    lstm_tagged16<<<dim3(128), dim3(256), 0, stream>>>(
        x, W_ih, W_hh, b_ih, b_hh, W_fc, b_fc, hor,
        (float*)d_out, (unsigned*)d_ws);
  } else {
    lstm_fallback<<<dim3(256), dim3(256), 0, stream>>>(
        x, W_ih, W_hh, b_ih, b_hh, W_fc, b_fc, hor,
        (float*)d_out, (unsigned short*)d_ws);
  }
}

// Round 4
// 3306.796 us; speedup vs baseline: 3.7095x; 1.2360x over previous
//
#include <hip/hip_runtime.h>

typedef __attribute__((ext_vector_type(8))) short bf16x8;   // 8 bf16 in 4 VGPRs
typedef __attribute__((ext_vector_type(4))) float f32x4;

#define NTT 512
#define NH  512
#define NIN 9
#define NO  3
#define MEMBERS 32    // WGs per group
#define MROWS   32    // batch rows per group
#define HPW     16    // hidden units per WG

__device__ __forceinline__ short f2bf(float f) {  // RNE fp32 -> bf16
  unsigned u = __builtin_bit_cast(unsigned, f);
  u = (u + 0x7fffu + ((u >> 16) & 1u)) >> 16;
  return (short)u;
}
__device__ __forceinline__ float bf2f(short s) {
  unsigned u = ((unsigned)(unsigned short)s) << 16;
  return __builtin_bit_cast(float, u);
}
__device__ __forceinline__ float sigf(float x) { return 1.f / (1.f + __expf(-x)); }
__device__ __forceinline__ float tanh_fast(float x) { return 1.f - 2.f / (1.f + __expf(2.f * x)); }

// ============================ TAGGED kernel =================================
// r9 geometry (proven 3093us): 256 WGs = 8 groups (32 batch rows) x 32 members
// (16 hidden each). ONE change vs r9: g = bid&7 / w = bid>>3 so a group's 32
// members land on the 32 CUs of ONE XCD under round-robin dispatch (bid%8 =
// XCD). Producer stores and consumer polls then meet in the XCD-shared L2
// (r3 evidence: FETCH_SIZE dropped 8x with this mapping) -> exchange RTT
// ~L2-class instead of L3-class. Perf heuristic only; correctness is
// tag-driven and mapping-independent.
__global__ __launch_bounds__(256, 1) void lstm_tagged(
    const float* __restrict__ x, const float* __restrict__ W_ih,
    const float* __restrict__ W_hh, const float* __restrict__ b_ih,
    const float* __restrict__ b_hh, const float* __restrict__ W_fc,
    const float* __restrict__ b_fc, const int* __restrict__ horizon,
    float* __restrict__ out, unsigned* __restrict__ ws32) {
  const int tid  = threadIdx.x;
  const int bid  = blockIdx.x;
  const int g    = bid & 7;    // group: batch rows [32g, 32g+32)  (== XCD id)
  const int w    = bid >> 3;   // member: hidden [16w, 16w+16)
  const int wid  = tid >> 6;   // wave = gate index (i,f,g,o)
  const int lane = tid & 63;
  const int l15  = lane & 15;
  const int quad = lane >> 4;
  const int hl   = tid & 15;   // update mapping: hidden-local
  const int b0   = tid >> 4;   // update mapping: rows b0, b0+16
  const int hg   = w * HPW + hl;

  // ws (u32): tagged h dbuf [2][8 grp][32 rows][512] = 2 x 512 KB
  unsigned* tbuf0 = ws32;
  unsigned* tbuf1 = ws32 + 131072;

  __shared__ __align__(16) unsigned short hbuf[32][520];  // 1040B rows, b128-aligned
  __shared__ __align__(16) float gbuf[4][16][36];         // [gate][hl][b] 144B stride
  __shared__ float fcbuf[4][32][4];                       // [wave(K-split)][b][o]
  __shared__ float xbuf[32][NIN];
  __shared__ float xw[64][NIN];                           // W_ih rows (gate*16+hl)
  __shared__ float bsl[64];

  // ---- persistent B fragments: W_hh hi/lo (fp32-exact weights) ----
  bf16x8 Bhi[16], Blo[16];
#pragma unroll
  for (int kt = 0; kt < 16; ++kt) {
    bf16x8 vh, vl;
    const int row = wid * NH + w * HPW + l15;
#pragma unroll
    for (int j = 0; j < 8; ++j) {
      int k = kt * 32 + quad * 8 + j;
      float v = W_hh[(size_t)row * NH + k];
      short hi = f2bf(v);
      vh[j] = hi; vl[j] = f2bf(v - bf2f(hi));
    }
    Bhi[kt] = vh; Blo[kt] = vl;
  }
  // fc tile: wave wid covers K quarter [128*wid, +128)
  bf16x8 Fhi[4], Flo[4];
#pragma unroll
  for (int kk = 0; kk < 4; ++kk) {
    bf16x8 vh, vl;
#pragma unroll
    for (int j = 0; j < 8; ++j) {
      int k = (wid * 4 + kk) * 32 + quad * 8 + j;
      float v = (l15 < NO) ? W_fc[(size_t)l15 * NH + k] : 0.f;
      short hi = f2bf(v);
      vh[j] = hi; vl[j] = f2bf(v - bf2f(hi));
    }
    Fhi[kk] = vh; Flo[kk] = vl;
  }
  if (tid < 64) {  // x-path weights + biases, fp32 exact, in LDS
    int grow = (tid >> 4) * NH + w * HPW + (tid & 15);
    bsl[tid] = b_ih[grow] + b_hh[grow];
#pragma unroll
    for (int k = 0; k < NIN; ++k) xw[tid][k] = W_ih[grow * NIN + k];
  }
  for (int i = tid; i < 8320; i += 256) ((unsigned*)hbuf)[i] = 0u;  // h_0 = 0
  const float bfc0 = b_fc[0], bfc1 = b_fc[1], bfc2 = b_fc[2];
  const int hor = *horizon;

  // ---- hoisted t-invariant index math ----
  const int r0c = tid / NIN, k0c = tid - r0c * NIN;          // x slice part 0
  const int i1c = tid + 256;
  const int r1c = i1c / NIN, k1c = i1c - r1c * NIN;          // x slice part 1
  const bool x0ok = (r0c < MROWS), x1ok = (i1c < MROWS * NIN);
  const float* xp0 = x + (size_t)(g * MROWS + (x0ok ? r0c : 0)) * NTT * NIN + k0c;
  const float* xp1 = x + (size_t)(g * MROWS + (x1ok ? r1c : 0)) * NTT * NIN + k1c;
  const int ob = tid / NO, oo = tid - ob * NO;               // out write mapping
  const bool ook = (w == 0) && (tid < MROWS * NO);
  const float obias = (oo == 0) ? bfc0 : (oo == 1) ? bfc1 : bfc2;
  float* op = out + ((size_t)(g * MROWS + ob) * NTT) * NO + oo;  // + t*NO per step
  __syncthreads();

  float cst[2] = {0.f, 0.f};
  int tmod = 0;

  for (int t = 0; t <= NTT; ++t) {
    // x_t slice: issue global loads NOW (regs), write LDS after MFMA.
    float xv0 = 0.f, xv1 = 0.f;
    if (t < NTT) {
      if (x0ok) xv0 = xp0[t * NIN];
      if (x1ok) xv1 = xp1[t * NIN];
    }

    // ---- MFMA: this gate's 16 cols over full K, both M-tiles; fc K-quarter ----
    f32x4 z4 = {0.f, 0.f, 0.f, 0.f};
    f32x4 accg[2] = {z4, z4}, accf[2] = {z4, z4};
#pragma unroll
    for (int kt = 0; kt < 16; ++kt) {
      bf16x8 a0 = *(const bf16x8*)&hbuf[l15][kt * 32 + quad * 8];
      bf16x8 a1 = *(const bf16x8*)&hbuf[16 + l15][kt * 32 + quad * 8];
      accg[0] = __builtin_amdgcn_mfma_f32_16x16x32_bf16(a0, Bhi[kt], accg[0], 0, 0, 0);
      accg[1] = __builtin_amdgcn_mfma_f32_16x16x32_bf16(a1, Bhi[kt], accg[1], 0, 0, 0);
      accg[0] = __builtin_amdgcn_mfma_f32_16x16x32_bf16(a0, Blo[kt], accg[0], 0, 0, 0);
      accg[1] = __builtin_amdgcn_mfma_f32_16x16x32_bf16(a1, Blo[kt], accg[1], 0, 0, 0);
      if ((kt >> 2) == wid) {
        int kk = kt & 3;
        accf[0] = __builtin_amdgcn_mfma_f32_16x16x32_bf16(a0, Fhi[kk], accf[0], 0, 0, 0);
        accf[1] = __builtin_amdgcn_mfma_f32_16x16x32_bf16(a1, Fhi[kk], accf[1], 0, 0, 0);
        accf[0] = __builtin_amdgcn_mfma_f32_16x16x32_bf16(a0, Flo[kk], accf[0], 0, 0, 0);
        accf[1] = __builtin_amdgcn_mfma_f32_16x16x32_bf16(a1, Flo[kk], accf[1], 0, 0, 0);
      }
    }
    // stage: D row(b) = mt*16 + quad*4 + r, col = l15
#pragma unroll
    for (int mt = 0; mt < 2; ++mt)
      *(f32x4*)&gbuf[wid][l15][mt * 16 + quad * 4] = accg[mt];
    if (l15 < NO) {
#pragma unroll
      for (int mt = 0; mt < 2; ++mt)
#pragma unroll
        for (int r = 0; r < 4; ++r) fcbuf[wid][mt * 16 + quad * 4 + r][l15] = accf[mt][r];
    }
    if (t < NTT) {
      if (x0ok) xbuf[r0c][k0c] = xv0;
      if (x1ok) xbuf[r1c][k1c] = xv1;
    }
    __syncthreads();

    if (t == NTT) {  // final fc only
      if (ook)
        op[(t - 1) * NO] =
            obias + fcbuf[0][ob][oo] + fcbuf[1][ob][oo] + fcbuf[2][ob][oo] + fcbuf[3][ob][oo];
      break;
    }

    const bool raw = (t < 5) || (tmod == 0);
    const unsigned tg = (unsigned)(t + 1);
    unsigned* dst = ((t & 1) ? tbuf1 : tbuf0) + (size_t)g * 16384;  // u32 slab

    // ---- cell update: thread owns (b0, hl) and (b0+16, hl) ----
#pragma unroll
    for (int e = 0; e < 2; ++e) {
      int b = b0 + 16 * e;
      float xin[NIN];
#pragma unroll
      for (int k = 0; k < NIN; ++k) xin[k] = xbuf[b][k];
      if (!raw) {
        xin[0] = bfc0 + fcbuf[0][b][0] + fcbuf[1][b][0] + fcbuf[2][b][0] + fcbuf[3][b][0];
        xin[1] = bfc1 + fcbuf[0][b][1] + fcbuf[1][b][1] + fcbuf[2][b][1] + fcbuf[3][b][1];
        xin[2] = bfc2 + fcbuf[0][b][2] + fcbuf[1][b][2] + fcbuf[2][b][2] + fcbuf[3][b][2];
      }
      float gv[4];
#pragma unroll
      for (int gg = 0; gg < 4; ++gg) {
        int r = gg * 16 + hl;
        float s = bsl[r] + gbuf[gg][hl][b];
#pragma unroll
        for (int k = 0; k < NIN; ++k) s += xin[k] * xw[r][k];
        gv[gg] = s;
      }
      float cn = sigf(gv[1]) * cst[e] + sigf(gv[0]) * tanh_fast(gv[2]);
      cst[e] = cn;
      float hn = sigf(gv[3]) * tanh_fast(cn);
      // tagged store: payload+tag in ONE u32 -> atomic consistency for free
      unsigned word = (unsigned)(unsigned short)f2bf(hn) | (tg << 16);
      __hip_atomic_store(&dst[(size_t)b * NH + hg], word,
                         __ATOMIC_RELAXED, __HIP_MEMORY_SCOPE_AGENT);
    }

    // out[t-1]: member 0 writes (off the exchange critical path)
    if (ook && t > 0)
      op[(t - 1) * NO] =
          obias + fcbuf[0][ob][oo] + fcbuf[1][ob][oo] + fcbuf[2][ob][oo] + fcbuf[3][ob][oo];

    // ---- exchange: all 32 loads in flight BEFORE any check; batched retry ----
    {
      const unsigned long long* src =
          (const unsigned long long*)(((t & 1) ? tbuf1 : tbuf0) + (size_t)g * 16384);
      const unsigned long long pat =
          ((unsigned long long)tg << 16) | ((unsigned long long)tg << 48);
      unsigned* hb32 = (unsigned*)hbuf;
      unsigned long long v[32];
#pragma unroll
      for (int j = 0; j < 32; ++j)   // one latency exposure, 32 loads in flight
        v[j] = __hip_atomic_load(src + tid + 256 * j,
                                 __ATOMIC_RELAXED, __HIP_MEMORY_SCOPE_AGENT);
      unsigned mask = 0u;
#pragma unroll
      for (int j = 0; j < 32; ++j)
        mask |= (((v[j] ^ pat) & 0xFFFF0000FFFF0000ULL) ? 1u : 0u) << j;
      while (__builtin_expect(mask != 0u, 0)) {
        // batched straggler reload: all failed words re-issued as independent loads
#pragma unroll
        for (int j = 0; j < 32; ++j)
          if (mask & (1u << j))
            v[j] = __hip_atomic_load(src + tid + 256 * j,
                                     __ATOMIC_RELAXED, __HIP_MEMORY_SCOPE_AGENT);
        unsigned m2 = 0u;
#pragma unroll
        for (int j = 0; j < 32; ++j)
          m2 |= (((v[j] ^ pat) & 0xFFFF0000FFFF0000ULL) ? 1u : 0u) << j;
        mask = m2;
      }
#pragma unroll
      for (int j = 0; j < 32; ++j) {
        const int q = tid + 256 * j;
        hb32[(q >> 8) * 260 + (q & 255)] =
            (unsigned)(v[j] & 0xFFFFu) | ((unsigned)(v[j] >> 32) << 16);
      }
      __syncthreads();
    }
    ++tmod; if (tmod == hor) tmod = 0;
  }
}

// ====================== FALLBACK kernel (r4 structure) ======================
__global__ __launch_bounds__(256, 1) void lstm_fallback(
    const float* __restrict__ x, const float* __restrict__ W_ih,
    const float* __restrict__ W_hh, const float* __restrict__ b_ih,
    const float* __restrict__ b_hh, const float* __restrict__ W_fc,
    const float* __restrict__ b_fc, const int* __restrict__ horizon,
    float* __restrict__ out, unsigned short* __restrict__ ws) {
  const int tid  = threadIdx.x;
  const int bid  = blockIdx.x;
  const int g    = bid >> 5;
  const int w    = bid & 31;
  const int wid  = tid >> 6;
  const int lane = tid & 63;
  const int l15  = lane & 15;
  const int quad = lane >> 4;
  const int hl   = tid & 15;
  const int b0   = tid >> 4;

  unsigned short* buf0 = ws;
  unsigned short* buf1 = ws + 131072;
  int* fl = (int*)(ws + 262144) + g * MEMBERS;

  __shared__ __align__(16) unsigned short hbuf[32][520];
  __shared__ __align__(16) float gbuf[4][16][36];
  __shared__ float fcbuf[4][32][4];
  __shared__ float xbuf[32][NIN];
  __shared__ float xw[64][NIN];
  __shared__ float bsl[64];

  bf16x8 Bhi[16], Blo[16];
#pragma unroll
  for (int kt = 0; kt < 16; ++kt) {
    bf16x8 vh, vl;
    const int row = wid * NH + w * HPW + l15;
#pragma unroll
    for (int j = 0; j < 8; ++j) {
      int k = kt * 32 + quad * 8 + j;
      float v = W_hh[(size_t)row * NH + k];
      short hi = f2bf(v);
      vh[j] = hi; vl[j] = f2bf(v - bf2f(hi));
    }
    Bhi[kt] = vh; Blo[kt] = vl;
  }
  bf16x8 Fhi[4], Flo[4];
#pragma unroll
  for (int kk = 0; kk < 4; ++kk) {
    bf16x8 vh, vl;
#pragma unroll
    for (int j = 0; j < 8; ++j) {
      int k = (wid * 4 + kk) * 32 + quad * 8 + j;
      float v = (l15 < NO) ? W_fc[(size_t)l15 * NH + k] : 0.f;
      short hi = f2bf(v);
      vh[j] = hi; vl[j] = f2bf(v - bf2f(hi));
    }
    Fhi[kk] = vh; Flo[kk] = vl;
  }
  if (tid < 64) {
    int grow = (tid >> 4) * NH + w * HPW + (tid & 15);
    bsl[tid] = b_ih[grow] + b_hh[grow];
#pragma unroll
    for (int k = 0; k < NIN; ++k) xw[tid][k] = W_ih[grow * NIN + k];
  }
  for (int i = tid; i < 8320; i += 256) ((unsigned*)hbuf)[i] = 0u;
  const float bfc0 = b_fc[0], bfc1 = b_fc[1], bfc2 = b_fc[2];
  const int hor = *horizon;
  __syncthreads();

  float cst[2] = {0.f, 0.f};
  int tmod = 0;

  for (int t = 0; t <= NTT; ++t) {
    float xv0 = 0.f, xv1 = 0.f;
    int r0 = 0, k0 = 0, r1 = 0, k1 = 0;
    if (t < NTT) {
      r0 = tid / NIN; k0 = tid - r0 * NIN;
      if (r0 < MROWS) xv0 = x[((size_t)(g * MROWS + r0) * NTT + t) * NIN + k0];
      int i1 = tid + 256;
      r1 = i1 / NIN; k1 = i1 - r1 * NIN;
      if (i1 < MROWS * NIN) xv1 = x[((size_t)(g * MROWS + r1) * NTT + t) * NIN + k1];
    }
    f32x4 z4 = {0.f, 0.f, 0.f, 0.f};
    f32x4 accg[2] = {z4, z4}, accf[2] = {z4, z4};
#pragma unroll
    for (int kt = 0; kt < 16; ++kt) {
      bf16x8 a0 = *(const bf16x8*)&hbuf[l15][kt * 32 + quad * 8];
      bf16x8 a1 = *(const bf16x8*)&hbuf[16 + l15][kt * 32 + quad * 8];
      accg[0] = __builtin_amdgcn_mfma_f32_16x16x32_bf16(a0, Bhi[kt], accg[0], 0, 0, 0);
      accg[1] = __builtin_amdgcn_mfma_f32_16x16x32_bf16(a1, Bhi[kt], accg[1], 0, 0, 0);
      accg[0] = __builtin_amdgcn_mfma_f32_16x16x32_bf16(a0, Blo[kt], accg[0], 0, 0, 0);
      accg[1] = __builtin_amdgcn_mfma_f32_16x16x32_bf16(a1, Blo[kt], accg[1], 0, 0, 0);
      if ((kt >> 2) == wid) {
        int kk = kt & 3;
        accf[0] = __builtin_amdgcn_mfma_f32_16x16x32_bf16(a0, Fhi[kk], accf[0], 0, 0, 0);
        accf[1] = __builtin_amdgcn_mfma_f32_16x16x32_bf16(a1, Fhi[kk], accf[1], 0, 0, 0);
        accf[0] = __builtin_amdgcn_mfma_f32_16x16x32_bf16(a0, Flo[kk], accf[0], 0, 0, 0);
        accf[1] = __builtin_amdgcn_mfma_f32_16x16x32_bf16(a1, Flo[kk], accf[1], 0, 0, 0);
      }
    }
#pragma unroll
    for (int mt = 0; mt < 2; ++mt)
      *(f32x4*)&gbuf[wid][l15][mt * 16 + quad * 4] = accg[mt];
    if (l15 < NO) {
#pragma unroll
      for (int mt = 0; mt < 2; ++mt)
#pragma unroll
        for (int r = 0; r < 4; ++r) fcbuf[wid][mt * 16 + quad * 4 + r][l15] = accf[mt][r];
    }
    if (t < NTT) {
      if (r0 < MROWS) xbuf[r0][k0] = xv0;
      if (tid < MROWS * NIN - 256) xbuf[r1][k1] = xv1;
    }
    __syncthreads();

    if (t == NTT) {
      if (w == 0 && tid < MROWS * NO) {
        int b = tid / NO, o = tid - b * NO;
        float bo = (o == 0) ? bfc0 : (o == 1) ? bfc1 : bfc2;
        out[((size_t)(g * MROWS + b) * NTT + (t - 1)) * NO + o] =
            bo + fcbuf[0][b][o] + fcbuf[1][b][o] + fcbuf[2][b][o] + fcbuf[3][b][o];
      }
      break;
    }

    const bool raw = (t < 5) || (tmod == 0);
    unsigned long long* nxt64 =
        (unsigned long long*)(((t & 1) ? buf1 : buf0) + (size_t)g * (MROWS * NH));
#pragma unroll
    for (int e = 0; e < 2; ++e) {
      int b = b0 + 16 * e;
      float xin[NIN];
#pragma unroll
      for (int k = 0; k < NIN; ++k) xin[k] = xbuf[b][k];
      if (!raw) {
        xin[0] = bfc0 + fcbuf[0][b][0] + fcbuf[1][b][0] + fcbuf[2][b][0] + fcbuf[3][b][0];
        xin[1] = bfc1 + fcbuf[0][b][1] + fcbuf[1][b][1] + fcbuf[2][b][1] + fcbuf[3][b][1];
        xin[2] = bfc2 + fcbuf[0][b][2] + fcbuf[1][b][2] + fcbuf[2][b][2] + fcbuf[3][b][2];
      }
      float gv[4];
#pragma unroll
      for (int gg = 0; gg < 4; ++gg) {
        int r = gg * 16 + hl;
        float s = bsl[r] + gbuf[gg][hl][b];
#pragma unroll
        for (int k = 0; k < NIN; ++k) s += xin[k] * xw[r][k];
        gv[gg] = s;
      }
      float cn = sigf(gv[1]) * cst[e] + sigf(gv[0]) * tanh_fast(gv[2]);
      cst[e] = cn;
      float hn = sigf(gv[3]) * tanh_fast(cn);
      unsigned hb16 = (unsigned)(unsigned short)f2bf(hn);
      unsigned pair = hb16 | ((unsigned)__shfl_xor((int)hb16, 1, 64) << 16);
      unsigned long long v64 =
          (unsigned long long)pair |
          ((unsigned long long)(unsigned)__shfl_xor((int)pair, 2, 64) << 32);
      if ((hl & 3) == 0)
        __hip_atomic_store(&nxt64[(size_t)b * 128 + w * 4 + (hl >> 2)], v64,
                           __ATOMIC_RELAXED, __HIP_MEMORY_SCOPE_AGENT);
    }
    asm volatile("s_waitcnt vmcnt(0)" ::: "memory");
    __syncthreads();

    if (tid == 0)
      __hip_atomic_store(&fl[w], t + 1, __ATOMIC_RELAXED, __HIP_MEMORY_SCOPE_AGENT);
    if (w == 0 && t > 0 && tid < MROWS * NO) {
      int b = tid / NO, o = tid - b * NO;
      float bo = (o == 0) ? bfc0 : (o == 1) ? bfc1 : bfc2;
      out[((size_t)(g * MROWS + b) * NTT + (t - 1)) * NO + o] =
          bo + fcbuf[0][b][o] + fcbuf[1][b][o] + fcbuf[2][b][o] + fcbuf[3][b][o];
    }
    if (tid < MEMBERS) {
      while (__hip_atomic_load(&fl[tid], __ATOMIC_RELAXED,
                               __HIP_MEMORY_SCOPE_AGENT) < t + 1)
        __builtin_amdgcn_s_sleep(1);
    }
    __syncthreads();

    const unsigned long long* src =
        (const unsigned long long*)(((t & 1) ? buf1 : buf0) + (size_t)g * (MROWS * NH));
#pragma unroll
    for (int j = 0; j < 16; ++j) {
      int idx = tid + 256 * j;
      unsigned long long v =
          __hip_atomic_load(src + idx, __ATOMIC_RELAXED, __HIP_MEMORY_SCOPE_AGENT);
      *(unsigned long long*)&hbuf[idx >> 7][(idx & 127) * 4] = v;
    }
    __syncthreads();
    ++tmod; if (tmod == hor) tmod = 0;
  }
}

extern "C" void kernel_launch(void* const* d_in, const int* in_sizes, int n_in,
                              void* d_out, int out_size, void* d_ws, size_t ws_size,
                              hipStream_t stream) {
  (void)in_sizes; (void)n_in; (void)out_size;
  const float* x    = (const float*)d_in[0];
  const float* W_ih = (const float*)d_in[1];
  const float* W_hh = (const float*)d_in[2];
  const float* b_ih = (const float*)d_in[3];
  const float* b_hh = (const float*)d_in[4];
  const float* W_fc = (const float*)d_in[5];
  const float* b_fc = (const float*)d_in[6];
  const int*   hor  = (const int*)d_in[7];
  if (ws_size >= (size_t)1048576) {
    lstm_tagged<<<dim3(256), dim3(256), 0, stream>>>(
        x, W_ih, W_hh, b_ih, b_hh, W_fc, b_fc, hor,
        (float*)d_out, (unsigned*)d_ws);
  } else {
    lstm_fallback<<<dim3(256), dim3(256), 0, stream>>>(
        x, W_ih, W_hh, b_ih, b_hh, W_fc, b_fc, hor,
        (float*)d_out, (unsigned short*)d_ws);
  }
}